// Round 11
// baseline (201.111 us; speedup 1.0000x reference)
//
#include <hip/hip_runtime.h>

// Performer (FAVOR+) causal linear attention, chunked-parallel, MFMA everywhere.
// B=4, H=16, L=2048, d_head=64, m=256, f32 in/out.
// R11 = R9 resubmit #2 (container infra failures R9/R10; kernel never ran):
// R3 pipeline, de-staged — RFT and S-prefix MFMA B-fragments read directly from
// global (L1/L2-resident / read-once) instead of LDS bounce. phase3 LDS
// 50.2->33.8 KB (4 blocks/CU), phase1 45->28.7 KB (5 blocks/CU); fewer barriers.

#define BB 4
#define HH 16
#define LL 2048
#define DH 64
#define DM 1024
#define MM 256
#define CC 64            // chunk length
#define NCH (LL / CC)    // 32 chunks

constexpr float SCALE = 0.17677669529663687f;  // 1024^-0.25
constexpr float NCF   = 0.0625f;               // 256^-0.5
constexpr float KEPS  = 1e-4f;
constexpr float NCFK  = NCF * KEPS;
constexpr float NSTB  = 1e-6f;

typedef __attribute__((ext_vector_type(8))) short s16x8;
typedef __attribute__((ext_vector_type(4))) float f32x4;

__device__ __forceinline__ float bf2f(unsigned short s) {
  return __uint_as_float(((unsigned)s) << 16);
}
__device__ __forceinline__ unsigned short f2bf(float f) {
  unsigned u = __float_as_uint(f);
  u += 0x7FFFu + ((u >> 16) & 1u);   // RNE
  return (unsigned short)(u >> 16);
}
__device__ __forceinline__ unsigned enc_key(float f) {
  unsigned u = __float_as_uint(f);
  return (u & 0x80000000u) ? ~u : (u | 0x80000000u);
}
__device__ __forceinline__ float dec_key(unsigned k) {
  unsigned u = (k & 0x80000000u) ? (k & 0x7FFFFFFFu) : ~k;
  return __uint_as_float(u);
}

// ---------------- kernel A: k_stab = max over all rows of h_k ----------------
__global__ __launch_bounds__(256) void kstab_kernel(const float* __restrict__ Kin,
                                                    unsigned int* __restrict__ wsu) {
  int lane = threadIdx.x & 63;
  int wave = threadIdx.x >> 6;
  int base = blockIdx.x * 64 + wave * 16;
  float m = -3.4e38f;
  for (int it = 0; it < 16; ++it) {
    int r = base + it;
    float v = Kin[(size_t)r * 64 + lane];
    float s = v * v;
    #pragma unroll
    for (int off = 32; off; off >>= 1) s += __shfl_xor(s, off, 64);
    float hk = -0.5f * (SCALE * SCALE) * s;
    m = fmaxf(m, hk);
  }
  __shared__ float wmax[4];
  if (lane == 0) wmax[wave] = m;
  __syncthreads();
  if (threadIdx.x == 0) {
    float mm = fmaxf(fmaxf(wmax[0], wmax[1]), fmaxf(wmax[2], wmax[3]));
    atomicMax(wsu, enc_key(mm));
  }
}

// ---------------- RF prep: RFTg[m][d] bf16, row=128B, XOR-swizzled ----------------
__global__ __launch_bounds__(256) void rft_prep(const float* __restrict__ RF,
                                                unsigned short* __restrict__ RFTg) {
  int m = threadIdx.x;
  float rv[64];
  #pragma unroll
  for (int d = 0; d < 64; ++d) rv[d] = RF[d * MM + m];  // coalesced across lanes
  unsigned swz = (unsigned)((m & 7) << 4);
  #pragma unroll
  for (int c16 = 0; c16 < 8; ++c16) {
    union { unsigned short u[8]; uint4 v; } pk_;
    #pragma unroll
    for (int i = 0; i < 8; ++i) pk_.u[i] = f2bf(rv[c16 * 8 + i]);
    unsigned byte = (unsigned)(m * 128) + (((unsigned)(c16 * 16)) ^ swz);
    *(uint4*)((char*)RFTg + byte) = pk_.v;
  }
}

// ---------------- phase1 (MFMA): per-chunk S^T partial (bf16) + Z partial ----------------
// LDS: KPl [m=128][c=64] bf16 16K | VT [d=64][c=64] bf16 8K | Zw 4K = 28.7K
__global__ __launch_bounds__(256) void phase1_kernel(const float* __restrict__ Kin,
                                                     const float* __restrict__ Vin,
                                                     const unsigned short* __restrict__ RFTg,
                                                     unsigned short* __restrict__ wsSb,
                                                     float* __restrict__ wsZ,
                                                     const unsigned int* __restrict__ wsu,
                                                     int bh0) {
  __shared__ __align__(16) char lds[28672];
  char* KPl = lds;
  char* VT  = lds + 16384;
  float* Zw = (float*)(lds + 24576);

  int slice = blockIdx.x / NCH;
  int c     = blockIdx.x % NCH;
  int bh = bh0 + slice, b = bh >> 4, h = bh & 15;
  const int t    = threadIdx.x;
  const int lane = t & 63;
  const int w    = t >> 6;
  const int rloc = lane & 15;
  const int kc0  = (lane >> 4) * 8;
  const int arow = 16 * w + rloc;
  const unsigned lgrp16 = (unsigned)((lane >> 4) * 16);
  const char* RFTb = (const char*)RFTg;
  float kst = dec_key(*wsu);

  // ---- K A-fragments + hk ----
  const float* krow = Kin + ((size_t)(b * LL + c * CC + arow)) * DM + h * DH;
  s16x8 kfrag[2];
  float ss = 0.f;
  #pragma unroll
  for (int kf = 0; kf < 2; ++kf) {
    float4 ka_ = *(const float4*)(krow + kf * 32 + kc0);
    float4 kb_ = *(const float4*)(krow + kf * 32 + kc0 + 4);
    float ks[8] = {ka_.x, ka_.y, ka_.z, ka_.w, kb_.x, kb_.y, kb_.z, kb_.w};
    #pragma unroll
    for (int i = 0; i < 8; ++i) {
      float kv = ks[i] * SCALE;
      ss += kv * kv;
      kfrag[kf][i] = (short)f2bf(kv);
    }
  }
  ss += __shfl_xor(ss, 16, 64);
  ss += __shfl_xor(ss, 32, 64);
  float hkv = -0.5f * ss;
  float hk4[4];
  #pragma unroll
  for (int r = 0; r < 4; ++r) hk4[r] = __shfl(hkv, (lane >> 4) * 4 + r, 64);

  // ---- V transpose -> VT[d][c] bf16 swizzled ----
  {
    const float* vbase = Vin + ((size_t)(b * LL + c * CC + w * 16)) * DM + h * DH + lane;
    float vv[16];
    #pragma unroll
    for (int i = 0; i < 16; ++i) vv[i] = vbase[(size_t)i * DM];
    unsigned swz = (unsigned)((lane & 7) << 4);
    #pragma unroll
    for (int q = 0; q < 2; ++q) {
      union { unsigned short u[8]; uint4 v; } pk_;
      #pragma unroll
      for (int i = 0; i < 8; ++i) pk_.u[i] = f2bf(vv[q * 8 + i]);
      unsigned byte = (unsigned)(lane * 128) + (((unsigned)(w * 32 + q * 16)) ^ swz);
      *(uint4*)(VT + byte) = pk_.v;
    }
  }

  for (int h2 = 0; h2 < 2; ++h2) {
    // ---- projection: pk = Ks * RF-half; B-frags direct from global RFTg ----
    f32x4 pk[8];
    #pragma unroll
    for (int i = 0; i < 8; ++i) pk[i] = (f32x4)0.f;
    #pragma unroll
    for (int mt = 0; mt < 8; ++mt) {
      int mloc = mt * 16 + rloc;
      unsigned rbyte = (unsigned)((h2 * 128 + mloc) * 128);
      unsigned swz = (unsigned)((mloc & 7) << 4);
      #pragma unroll
      for (int kf = 0; kf < 2; ++kf) {
        s16x8 bf_ = *(const s16x8*)(RFTb + rbyte + (((unsigned)(kf * 64) + lgrp16) ^ swz));
        pk[mt] = __builtin_amdgcn_mfma_f32_16x16x32_bf16(kfrag[kf], bf_, pk[mt], 0, 0, 0);
      }
    }
    if (h2) __syncthreads();  // protect KPl from h2=0's S^T reads
    // ---- exp -> KpT [m][c] swizzled; Z partials ----
    #pragma unroll
    for (int mt = 0; mt < 8; ++mt) {
      int mloc = mt * 16 + rloc;
      float zp = 0.f;
      #pragma unroll
      for (int r = 0; r < 4; ++r) {
        int cpos = 16 * w + (lane >> 4) * 4 + r;
        float kpv = NCF * __expf(hk4[r] + pk[mt][r] - kst) + NCFK;
        zp += kpv;
        unsigned byte = (unsigned)(mloc * 128) +
                        (((unsigned)(cpos * 2)) ^ ((unsigned)((mloc & 7) << 4)));
        *(unsigned short*)(KPl + byte) = f2bf(kpv);
      }
      zp += __shfl_xor(zp, 16, 64);
      zp += __shfl_xor(zp, 32, 64);
      if (lane < 16) Zw[w * 256 + h2 * 128 + mt * 16 + lane] = zp;
    }
    __syncthreads();  // KPl (and first-iter VT) visible

    // ---- S^T = VT . KpT^T : D[d-row][m-col], contraction over c ----
    f32x4 sacc[8];
    #pragma unroll
    for (int i = 0; i < 8; ++i) sacc[i] = (f32x4)0.f;
    s16x8 af[2];
    {
      int drow = w * 16 + rloc;
      unsigned rbyte = (unsigned)(drow * 128);
      unsigned swz = (unsigned)((drow & 7) << 4);
      #pragma unroll
      for (int kf = 0; kf < 2; ++kf)
        af[kf] = *(const s16x8*)(VT + rbyte + (((unsigned)(kf * 64) + lgrp16) ^ swz));
    }
    #pragma unroll
    for (int mt = 0; mt < 8; ++mt) {
      int mrow = mt * 16 + rloc;
      unsigned rbyte = (unsigned)(mrow * 128);
      unsigned swz = (unsigned)((mrow & 7) << 4);
      #pragma unroll
      for (int kf = 0; kf < 2; ++kf) {
        s16x8 bf_ = *(const s16x8*)(KPl + rbyte + (((unsigned)(kf * 64) + lgrp16) ^ swz));
        sacc[mt] = __builtin_amdgcn_mfma_f32_16x16x32_bf16(af[kf], bf_, sacc[mt], 0, 0, 0);
      }
    }
    // ---- write S^T partial bf16 [d=64][m=256] plain layout ----
    unsigned short* sdst = wsSb + (size_t)(slice * NCH + c) * 16384;
    #pragma unroll
    for (int mt = 0; mt < 8; ++mt) {
      #pragma unroll
      for (int r = 0; r < 4; ++r) {
        int d = w * 16 + (lane >> 4) * 4 + r;
        int m = h2 * 128 + mt * 16 + rloc;
        sdst[d * 256 + m] = f2bf(sacc[mt][r]);
      }
    }
  }
  __syncthreads();
  // ---- Z finalize (sum 4 wave partials) ----
  float z = Zw[t] + Zw[256 + t] + Zw[512 + t] + Zw[768 + t];
  wsZ[(size_t)(slice * NCH + c) * MM + t] = z;
}

// ---------------- phase2: exclusive prefix scan; writes phase3-ready swizzled bf16 ----------------
__global__ __launch_bounds__(256) void scan_kernel(const unsigned short* __restrict__ wsSb,
                                                   unsigned short* __restrict__ wsPb,
                                                   float* __restrict__ wsZ) {
  int slice = blockIdx.x >> 3, part = blockIdx.x & 7;
  const int t = threadIdx.x;
  int d_l = t >> 5, moct = t & 31;
  int d = part * 8 + d_l, m0 = moct * 8;
  int half = m0 >> 7, m_l = m0 & 127;
  const unsigned short* srcb = wsSb + (size_t)slice * NCH * 16384 + d * 256 + m0;
  char* dstb = (char*)wsPb + ((size_t)slice * NCH * 2 + half) * 16384 +
               (unsigned)(d * 256) + (((unsigned)(m_l * 2)) ^ ((unsigned)((d & 7) << 4)));
  float run[8] = {0.f, 0.f, 0.f, 0.f, 0.f, 0.f, 0.f, 0.f};
  for (int c = 0; c < NCH; ++c) {
    uint4 v = *(const uint4*)(srcb + (size_t)c * 16384);
    union { unsigned short u[8]; uint4 q; } o;
    #pragma unroll
    for (int i = 0; i < 8; ++i) o.u[i] = f2bf(run[i]);
    *(uint4*)(dstb + (size_t)c * 32768) = o.q;
    const unsigned short* pv = (const unsigned short*)&v;
    #pragma unroll
    for (int i = 0; i < 8; ++i) run[i] += bf2f(pv[i]);
  }
  if (part == 0) {
    for (int e = t; e < MM; e += 256) {
      float zr = 0.f;
      for (int c = 0; c < NCH; ++c) {
        size_t idx = (size_t)slice * NCH * MM + (size_t)c * MM + e;
        float x = wsZ[idx];
        wsZ[idx] = zr;
        zr += x;
      }
    }
  }
}

// ---------------- phase3: MFMA outputs per (b,h,chunk) ----------------
// LDS: QPl 16K (later Amask 8K + VT 8K) | KPl 16K | ZL 1K = 33.8K
__global__ __launch_bounds__(256) void phase3_kernel(const float* __restrict__ Qin,
                                                     const float* __restrict__ Kin,
                                                     const float* __restrict__ Vin,
                                                     const unsigned short* __restrict__ RFTg,
                                                     const unsigned short* __restrict__ wsPb,
                                                     const float* __restrict__ wsZ,
                                                     const unsigned int* __restrict__ wsu,
                                                     float* __restrict__ Out,
                                                     int bh0) {
  __shared__ __align__(16) char lds[33792];
  char* QPl = lds;
  char* KPl = lds + 16384;
  float* ZL = (float*)(lds + 32768);

  int slice = blockIdx.x / NCH;
  int c     = blockIdx.x % NCH;
  int bh = bh0 + slice, b = bh >> 4, h = bh & 15;
  const int t    = threadIdx.x;
  const int lane = t & 63;
  const int w    = t >> 6;

  ZL[t] = wsZ[(size_t)(slice * NCH + c) * MM + t];
  float kst = dec_key(*wsu);

  const int rloc = lane & 15;
  const int kc0  = (lane >> 4) * 8;
  const int arow = 16 * w + rloc;
  const char* RFTb = (const char*)RFTg;
  const char* Sprev = (const char*)wsPb + ((size_t)(slice * NCH + c) * 2) * 16384;
  const float* qrow = Qin + ((size_t)(b * LL + c * CC + arow)) * DM + h * DH;
  const float* krow = Kin + ((size_t)(b * LL + c * CC + arow)) * DM + h * DH;

  s16x8 qfrag[2], kfrag[2];
  float ss = 0.f;
  #pragma unroll
  for (int kf = 0; kf < 2; ++kf) {
    float4 qa_ = *(const float4*)(qrow + kf * 32 + kc0);
    float4 qb_ = *(const float4*)(qrow + kf * 32 + kc0 + 4);
    float4 ka_ = *(const float4*)(krow + kf * 32 + kc0);
    float4 kb_ = *(const float4*)(krow + kf * 32 + kc0 + 4);
    float qs[8] = {qa_.x, qa_.y, qa_.z, qa_.w, qb_.x, qb_.y, qb_.z, qb_.w};
    float ks[8] = {ka_.x, ka_.y, ka_.z, ka_.w, kb_.x, kb_.y, kb_.z, kb_.w};
    #pragma unroll
    for (int i = 0; i < 8; ++i) {
      float qv = qs[i] * SCALE, kv = ks[i] * SCALE;
      ss += kv * kv;
      qfrag[kf][i] = (short)f2bf(qv);
      kfrag[kf][i] = (short)f2bf(kv);
    }
  }
  ss += __shfl_xor(ss, 16, 64);
  ss += __shfl_xor(ss, 32, 64);
  float hkv = -0.5f * ss;

  f32x4 Aacc[4], Oacc[4];
  #pragma unroll
  for (int i = 0; i < 4; ++i) { Aacc[i] = (f32x4)0.f; Oacc[i] = (f32x4)0.f; }
  float den1[4] = {0.f, 0.f, 0.f, 0.f};
  float den2[4] = {0.f, 0.f, 0.f, 0.f};

  float hk4[4];
  #pragma unroll
  for (int r = 0; r < 4; ++r) hk4[r] = __shfl(hkv, (lane >> 4) * 4 + r, 64);

  const unsigned lgrp16 = (unsigned)((lane >> 4) * 16);

  __syncthreads();  // ZL visible to all (cross-thread reads below)

  for (int h2 = 0; h2 < 2; ++h2) {
    // ---- projections: P = Qs*RF, Ks*RF; B-frags direct from global RFTg ----
    f32x4 pq[8], pk[8];
    #pragma unroll
    for (int i = 0; i < 8; ++i) { pq[i] = (f32x4)0.f; pk[i] = (f32x4)0.f; }
    #pragma unroll
    for (int mt = 0; mt < 8; ++mt) {
      int mloc = mt * 16 + rloc;
      unsigned rbyte = (unsigned)(h2 * 16384 + mloc * 128);
      unsigned swz = (unsigned)((mloc & 7) << 4);
      #pragma unroll
      for (int kf = 0; kf < 2; ++kf) {
        s16x8 bf_ = *(const s16x8*)(RFTb + rbyte + (((unsigned)(kf * 64) + lgrp16) ^ swz));
        pq[mt] = __builtin_amdgcn_mfma_f32_16x16x32_bf16(qfrag[kf], bf_, pq[mt], 0, 0, 0);
        pk[mt] = __builtin_amdgcn_mfma_f32_16x16x32_bf16(kfrag[kf], bf_, pk[mt], 0, 0, 0);
      }
    }
    if (h2) __syncthreads();  // h2=0 readers of QPl/KPl done before overwrite
    // ---- exp, pack to QP/KP, den2 partials ----
    #pragma unroll
    for (int mt = 0; mt < 8; ++mt) {
      int mloc = mt * 16 + rloc;
      #pragma unroll
      for (int r = 0; r < 4; ++r) {
        int row = 16 * w + (lane >> 4) * 4 + r;
        float qpv = NCF * __expf(pq[mt][r]) + NCFK;
        float kpv = NCF * __expf(hk4[r] + pk[mt][r] - kst) + NCFK;
        unsigned byte = (unsigned)(row * 256) +
                        (((unsigned)(mloc * 2)) ^ ((unsigned)((row & 7) << 4)));
        *(unsigned short*)(QPl + byte) = f2bf(qpv);
        *(unsigned short*)(KPl + byte) = f2bf(kpv);
        den2[r] += qpv * ZL[h2 * 128 + mloc];
      }
    }
    __syncthreads();

    // ---- Qp A-frags (reused for A-MFMA and O2) ----
    s16x8 qa[4];
    {
      unsigned rbyte = (unsigned)(arow * 256);
      unsigned swz = (unsigned)((arow & 7) << 4);
      #pragma unroll
      for (int kf = 0; kf < 4; ++kf)
        qa[kf] = *(const s16x8*)(QPl + rbyte + (((unsigned)(kf * 64) + lgrp16) ^ swz));
    }
    // ---- A += Qp * Kp^T (only tiles ct <= w are unmasked) ----
    for (int ct = 0; ct <= w; ++ct) {
      int rowb = ct * 16 + rloc;
      unsigned rbyte = (unsigned)(rowb * 256);
      unsigned swz = (unsigned)((rowb & 7) << 4);
      #pragma unroll
      for (int kf = 0; kf < 4; ++kf) {
        s16x8 bf_ = *(const s16x8*)(KPl + rbyte + (((unsigned)(kf * 64) + lgrp16) ^ swz));
        Aacc[ct] = __builtin_amdgcn_mfma_f32_16x16x32_bf16(qa[kf], bf_, Aacc[ct], 0, 0, 0);
      }
    }
    // ---- O += Qp * S_prev ; B-frags direct from global wsPb (read-once) ----
    {
      const char* ssrc = Sprev + (size_t)h2 * 16384;
      #pragma unroll
      for (int ct = 0; ct < 4; ++ct) {
        int rowb = ct * 16 + rloc;   // d-row of ST
        unsigned rbyte = (unsigned)(rowb * 256);
        unsigned swz = (unsigned)((rowb & 7) << 4);
        #pragma unroll
        for (int kf = 0; kf < 4; ++kf) {
          s16x8 bf_ = *(const s16x8*)(ssrc + rbyte + (((unsigned)(kf * 64) + lgrp16) ^ swz));
          Oacc[ct] = __builtin_amdgcn_mfma_f32_16x16x32_bf16(qa[kf], bf_, Oacc[ct], 0, 0, 0);
        }
      }
    }
  }

  __syncthreads();  // all QPl/KPl reads done; QPl becomes Amask+VT

  // ---- mask A, den1 partials, write Amask (bf16, swizzled) at QPl[0..8K) ----
  #pragma unroll
  for (int ct = 0; ct < 4; ++ct) {
    #pragma unroll
    for (int r = 0; r < 4; ++r) {
      int row = 16 * w + (lane >> 4) * 4 + r;
      int col = ct * 16 + rloc;
      float av = (ct <= w && col <= row) ? Aacc[ct][r] : 0.f;
      den1[r] += av;
      unsigned byte = (unsigned)(row * 128) +
                      (((unsigned)(col * 2)) ^ ((unsigned)((row & 7) << 4)));
      *(unsigned short*)(QPl + byte) = f2bf(av);
    }
  }
  // ---- transpose V -> QPl[8K..16K) (bf16, swizzled) ----
  {
    const float* vbase = Vin + ((size_t)(b * LL + c * CC + w * 16)) * DM + h * DH + lane;
    float vv[16];
    #pragma unroll
    for (int i = 0; i < 16; ++i) vv[i] = vbase[(size_t)i * DM];
    unsigned swz = (unsigned)((lane & 7) << 4);
    #pragma unroll
    for (int q = 0; q < 2; ++q) {
      union { unsigned short u[8]; uint4 v; } pk_;
      #pragma unroll
      for (int i = 0; i < 8; ++i) pk_.u[i] = f2bf(vv[q * 8 + i]);
      unsigned byte = 8192u + (unsigned)(lane * 128) + (((unsigned)(w * 32 + q * 16)) ^ swz);
      *(uint4*)(QPl + byte) = pk_.v;
    }
  }
  __syncthreads();

  // ---- O += mask(A) * V ----
  {
    int nkf = (w >= 2) ? 2 : 1;
    unsigned arbyte = (unsigned)(arow * 128);
    unsigned aswz = (unsigned)((arow & 7) << 4);
    for (int kf = 0; kf < nkf; ++kf) {
      s16x8 af = *(const s16x8*)(QPl + arbyte + (((unsigned)(kf * 64) + lgrp16) ^ aswz));
      #pragma unroll
      for (int ct = 0; ct < 4; ++ct) {
        int rowv = ct * 16 + rloc;
        unsigned byte = 8192u + (unsigned)(rowv * 128) +
                        (((unsigned)(kf * 64) + lgrp16) ^ ((unsigned)((rowv & 7) << 4)));
        s16x8 vf = *(const s16x8*)(QPl + byte);
        Oacc[ct] = __builtin_amdgcn_mfma_f32_16x16x32_bf16(af, vf, Oacc[ct], 0, 0, 0);
      }
    }
  }

  // ---- denominator reduce + epilogue ----
  float inv[4];
  #pragma unroll
  for (int r = 0; r < 4; ++r) {
    float dv = den1[r] + den2[r];
    dv += __shfl_xor(dv, 1, 64);
    dv += __shfl_xor(dv, 2, 64);
    dv += __shfl_xor(dv, 4, 64);
    dv += __shfl_xor(dv, 8, 64);
    if (fabsf(dv) <= NSTB) dv += 2.f * NSTB;
    inv[r] = 1.0f / dv;
  }
  #pragma unroll
  for (int r = 0; r < 4; ++r) {
    int row = 16 * w + (lane >> 4) * 4 + r;
    size_t g = ((size_t)(b * LL + c * CC + row)) * DM + h * DH;
    #pragma unroll
    for (int ct = 0; ct < 4; ++ct) {
      Out[g + ct * 16 + rloc] = Oacc[ct][r] * inv[r];
    }
  }
}

extern "C" void kernel_launch(void* const* d_in, const int* in_sizes, int n_in,
                              void* d_out, int out_size, void* d_ws, size_t ws_size,
                              hipStream_t stream) {
  const float* Q  = (const float*)d_in[0];
  const float* K  = (const float*)d_in[1];
  const float* V  = (const float*)d_in[2];
  const float* RF = (const float*)d_in[3];
  float* Out = (float*)d_out;
  unsigned int* wsu = (unsigned int*)d_ws;

  const size_t RESV = 1024;
  const size_t RFTB = 32768;  // RFTg bf16 [256][64] swizzled
  const size_t perSlice = (size_t)NCH * 16384 * 2   // wsSb bytes
                        + (size_t)NCH * 2 * 16384   // wsPb bytes
                        + (size_t)NCH * MM * 4;     // wsZ bytes
  int G = BB * HH;  // 64
  while (G > 1 && RESV + RFTB + (size_t)G * perSlice > ws_size) G >>= 1;

  unsigned short* RFTg = (unsigned short*)((char*)d_ws + RESV);
  unsigned short* wsSb = (unsigned short*)((char*)d_ws + RESV + RFTB);
  unsigned short* wsPb = wsSb + (size_t)G * NCH * 16384;
  float* wsZ = (float*)((char*)wsPb + (size_t)G * NCH * 2 * 16384);

  hipMemsetAsync(d_ws, 0, 4, stream);  // init k_stab atomicMax key
  hipLaunchKernelGGL(kstab_kernel, dim3(2048), dim3(256), 0, stream, K, wsu);
  hipLaunchKernelGGL(rft_prep, dim3(1), dim3(256), 0, stream, RF, RFTg);
  for (int bh0 = 0; bh0 < BB * HH; bh0 += G) {
    hipLaunchKernelGGL(phase1_kernel, dim3(G * NCH), dim3(256), 0, stream,
                       K, V, RFTg, wsSb, wsZ, wsu, bh0);
    hipLaunchKernelGGL(scan_kernel, dim3(G * 8), dim3(256), 0, stream, wsSb, wsPb, wsZ);
    hipLaunchKernelGGL(phase3_kernel, dim3(G * NCH), dim3(256), 0, stream,
                       Q, K, V, RFTg, wsPb, wsZ, wsu, Out, bh0);
  }
}

// Round 14
// 159.362 us; speedup vs baseline: 1.2620x; 1.2620x over previous
//
#include <hip/hip_runtime.h>

// Performer (FAVOR+) causal linear attention, chunked-parallel, MFMA everywhere.
// B=4, H=16, L=2048, d_head=64, m=256, f32 in/out.
// R14 = R12 resubmit #2 (container infra failures; kernel never ran):
// R3 pipeline (verified 163.5us) + VALU diet:
//  - f2bf via native __bf16 cast (compiler fuses to v_cvt_pk_bf16_f32)
//  - exp-argument folding: NCF*exp(x)+eps = exp(x+lnNCF)+eps; -kst folded into hkb

#define BB 4
#define HH 16
#define LL 2048
#define DH 64
#define DM 1024
#define MM 256
#define CC 64            // chunk length
#define NCH (LL / CC)    // 32 chunks

constexpr float SCALE = 0.17677669529663687f;  // 1024^-0.25
constexpr float NCF   = 0.0625f;               // 256^-0.5
constexpr float LNCF  = -2.772588722239781f;   // ln(NCF)
constexpr float KEPS  = 1e-4f;
constexpr float NCFK  = NCF * KEPS;
constexpr float NSTB  = 1e-6f;

typedef __attribute__((ext_vector_type(8))) short s16x8;
typedef __attribute__((ext_vector_type(4))) float f32x4;

__device__ __forceinline__ float bf2f(unsigned short s) {
  return __uint_as_float(((unsigned)s) << 16);
}
__device__ __forceinline__ unsigned short f2bf(float f) {
  return __builtin_bit_cast(unsigned short, static_cast<__bf16>(f));  // RNE
}
__device__ __forceinline__ unsigned enc_key(float f) {
  unsigned u = __float_as_uint(f);
  return (u & 0x80000000u) ? ~u : (u | 0x80000000u);
}
__device__ __forceinline__ float dec_key(unsigned k) {
  unsigned u = (k & 0x80000000u) ? (k & 0x7FFFFFFFu) : ~k;
  return __uint_as_float(u);
}

// ---------------- kernel A: k_stab = max over all rows of h_k ----------------
__global__ __launch_bounds__(256) void kstab_kernel(const float* __restrict__ Kin,
                                                    unsigned int* __restrict__ wsu) {
  int lane = threadIdx.x & 63;
  int wave = threadIdx.x >> 6;
  int base = blockIdx.x * 64 + wave * 16;
  float m = -3.4e38f;
  for (int it = 0; it < 16; ++it) {
    int r = base + it;
    float v = Kin[(size_t)r * 64 + lane];
    float s = v * v;
    #pragma unroll
    for (int off = 32; off; off >>= 1) s += __shfl_xor(s, off, 64);
    float hk = -0.5f * (SCALE * SCALE) * s;
    m = fmaxf(m, hk);
  }
  __shared__ float wmax[4];
  if (lane == 0) wmax[wave] = m;
  __syncthreads();
  if (threadIdx.x == 0) {
    float mm = fmaxf(fmaxf(wmax[0], wmax[1]), fmaxf(wmax[2], wmax[3]));
    atomicMax(wsu, enc_key(mm));
  }
}

// ---------------- RF prep: RFTg[m][d] bf16, row=128B, XOR-swizzled ----------------
__global__ __launch_bounds__(256) void rft_prep(const float* __restrict__ RF,
                                                unsigned short* __restrict__ RFTg) {
  int m = threadIdx.x;
  float rv[64];
  #pragma unroll
  for (int d = 0; d < 64; ++d) rv[d] = RF[d * MM + m];  // coalesced across lanes
  unsigned swz = (unsigned)((m & 7) << 4);
  #pragma unroll
  for (int c16 = 0; c16 < 8; ++c16) {
    union { unsigned short u[8]; uint4 v; } pk_;
    #pragma unroll
    for (int i = 0; i < 8; ++i) pk_.u[i] = f2bf(rv[c16 * 8 + i]);
    unsigned byte = (unsigned)(m * 128) + (((unsigned)(c16 * 16)) ^ swz);
    *(uint4*)((char*)RFTg + byte) = pk_.v;
  }
}

// ---------------- phase1 (MFMA): per-chunk S^T partial (bf16) + Z partial ----------------
// LDS: U0 (RFT half) 16K | KPl [m=128][c=64] bf16 16K | VT [d=64][c=64] bf16 8K | Zw 4K
__global__ __launch_bounds__(256) void phase1_kernel(const float* __restrict__ Kin,
                                                     const float* __restrict__ Vin,
                                                     const unsigned short* __restrict__ RFTg,
                                                     unsigned short* __restrict__ wsSb,
                                                     float* __restrict__ wsZ,
                                                     const unsigned int* __restrict__ wsu,
                                                     int bh0) {
  __shared__ __align__(16) char lds[45056];
  char* U0  = lds;
  char* KPl = lds + 16384;
  char* VT  = lds + 32768;
  float* Zw = (float*)(lds + 40960);

  int slice = blockIdx.x / NCH;
  int c     = blockIdx.x % NCH;
  int bh = bh0 + slice, b = bh >> 4, h = bh & 15;
  const int t    = threadIdx.x;
  const int lane = t & 63;
  const int w    = t >> 6;
  const int rloc = lane & 15;
  const int kc0  = (lane >> 4) * 8;
  const int arow = 16 * w + rloc;
  const unsigned lgrp16 = (unsigned)((lane >> 4) * 16);
  float kst = dec_key(*wsu);

  // ---- K A-fragments + hk ----
  const float* krow = Kin + ((size_t)(b * LL + c * CC + arow)) * DM + h * DH;
  s16x8 kfrag[2];
  float ss = 0.f;
  #pragma unroll
  for (int kf = 0; kf < 2; ++kf) {
    float4 ka_ = *(const float4*)(krow + kf * 32 + kc0);
    float4 kb_ = *(const float4*)(krow + kf * 32 + kc0 + 4);
    float ks[8] = {ka_.x, ka_.y, ka_.z, ka_.w, kb_.x, kb_.y, kb_.z, kb_.w};
    #pragma unroll
    for (int i = 0; i < 8; ++i) {
      float kv = ks[i] * SCALE;
      ss += kv * kv;
      kfrag[kf][i] = (short)f2bf(kv);
    }
  }
  ss += __shfl_xor(ss, 16, 64);
  ss += __shfl_xor(ss, 32, 64);
  float hkv = -0.5f * ss;
  float hkb[4];
  #pragma unroll
  for (int r = 0; r < 4; ++r)
    hkb[r] = __shfl(hkv, (lane >> 4) * 4 + r, 64) - kst + LNCF;  // folded

  // ---- V transpose -> VT[d][c] bf16 swizzled ----
  {
    const float* vbase = Vin + ((size_t)(b * LL + c * CC + w * 16)) * DM + h * DH + lane;
    float vv[16];
    #pragma unroll
    for (int i = 0; i < 16; ++i) vv[i] = vbase[(size_t)i * DM];
    unsigned swz = (unsigned)((lane & 7) << 4);
    #pragma unroll
    for (int q = 0; q < 2; ++q) {
      union { unsigned short u[8]; uint4 v; } pk_;
      #pragma unroll
      for (int i = 0; i < 8; ++i) pk_.u[i] = f2bf(vv[q * 8 + i]);
      unsigned byte = (unsigned)(lane * 128) + (((unsigned)(w * 32 + q * 16)) ^ swz);
      *(uint4*)(VT + byte) = pk_.v;
    }
  }

  for (int h2 = 0; h2 < 2; ++h2) {
    __syncthreads();
    {  // RFT half -> U0 (pre-swizzled, linear)
      const uint4* src = (const uint4*)(RFTg + (size_t)h2 * 8192);
      uint4* dst = (uint4*)U0;
      #pragma unroll
      for (int r2 = 0; r2 < 4; ++r2) dst[t + 256 * r2] = src[t + 256 * r2];
    }
    __syncthreads();

    // ---- projection: pk = Ks * RF-half ----
    f32x4 pk[8];
    #pragma unroll
    for (int i = 0; i < 8; ++i) pk[i] = (f32x4)0.f;
    #pragma unroll
    for (int mt = 0; mt < 8; ++mt) {
      int mloc = mt * 16 + rloc;
      unsigned rbyte = (unsigned)(mloc * 128);
      unsigned swz = (unsigned)((mloc & 7) << 4);
      #pragma unroll
      for (int kf = 0; kf < 2; ++kf) {
        s16x8 bf_ = *(const s16x8*)(U0 + rbyte + (((unsigned)(kf * 64) + lgrp16) ^ swz));
        pk[mt] = __builtin_amdgcn_mfma_f32_16x16x32_bf16(kfrag[kf], bf_, pk[mt], 0, 0, 0);
      }
    }
    // ---- exp -> KpT [m][c] swizzled; Z partials ----
    #pragma unroll
    for (int mt = 0; mt < 8; ++mt) {
      int mloc = mt * 16 + rloc;
      float zp = 0.f;
      #pragma unroll
      for (int r = 0; r < 4; ++r) {
        int cpos = 16 * w + (lane >> 4) * 4 + r;
        float kpv = __expf(hkb[r] + pk[mt][r]) + NCFK;
        zp += kpv;
        unsigned byte = (unsigned)(mloc * 128) +
                        (((unsigned)(cpos * 2)) ^ ((unsigned)((mloc & 7) << 4)));
        *(unsigned short*)(KPl + byte) = f2bf(kpv);
      }
      zp += __shfl_xor(zp, 16, 64);
      zp += __shfl_xor(zp, 32, 64);
      if (lane < 16) Zw[w * 256 + h2 * 128 + mt * 16 + lane] = zp;
    }
    __syncthreads();

    // ---- S^T = VT . KpT^T : D[d-row][m-col], contraction over c ----
    f32x4 sacc[8];
    #pragma unroll
    for (int i = 0; i < 8; ++i) sacc[i] = (f32x4)0.f;
    s16x8 af[2];
    {
      int drow = w * 16 + rloc;
      unsigned rbyte = (unsigned)(drow * 128);
      unsigned swz = (unsigned)((drow & 7) << 4);
      #pragma unroll
      for (int kf = 0; kf < 2; ++kf)
        af[kf] = *(const s16x8*)(VT + rbyte + (((unsigned)(kf * 64) + lgrp16) ^ swz));
    }
    #pragma unroll
    for (int mt = 0; mt < 8; ++mt) {
      int mrow = mt * 16 + rloc;
      unsigned rbyte = (unsigned)(mrow * 128);
      unsigned swz = (unsigned)((mrow & 7) << 4);
      #pragma unroll
      for (int kf = 0; kf < 2; ++kf) {
        s16x8 bf_ = *(const s16x8*)(KPl + rbyte + (((unsigned)(kf * 64) + lgrp16) ^ swz));
        sacc[mt] = __builtin_amdgcn_mfma_f32_16x16x32_bf16(af[kf], bf_, sacc[mt], 0, 0, 0);
      }
    }
    // ---- write S^T partial bf16 [d=64][m=256] plain layout ----
    unsigned short* sdst = wsSb + (size_t)(slice * NCH + c) * 16384;
    #pragma unroll
    for (int mt = 0; mt < 8; ++mt) {
      #pragma unroll
      for (int r = 0; r < 4; ++r) {
        int d = w * 16 + (lane >> 4) * 4 + r;
        int m = h2 * 128 + mt * 16 + rloc;
        sdst[d * 256 + m] = f2bf(sacc[mt][r]);
      }
    }
  }
  __syncthreads();
  // ---- Z finalize (sum 4 wave partials) ----
  float z = Zw[t] + Zw[256 + t] + Zw[512 + t] + Zw[768 + t];
  wsZ[(size_t)(slice * NCH + c) * MM + t] = z;
}

// ---------------- phase2: exclusive prefix scan; writes phase3-ready swizzled bf16 ----------------
__global__ __launch_bounds__(256) void scan_kernel(const unsigned short* __restrict__ wsSb,
                                                   unsigned short* __restrict__ wsPb,
                                                   float* __restrict__ wsZ) {
  int slice = blockIdx.x >> 3, part = blockIdx.x & 7;
  const int t = threadIdx.x;
  int d_l = t >> 5, moct = t & 31;
  int d = part * 8 + d_l, m0 = moct * 8;
  int half = m0 >> 7, m_l = m0 & 127;
  const unsigned short* srcb = wsSb + (size_t)slice * NCH * 16384 + d * 256 + m0;
  char* dstb = (char*)wsPb + ((size_t)slice * NCH * 2 + half) * 16384 +
               (unsigned)(d * 256) + (((unsigned)(m_l * 2)) ^ ((unsigned)((d & 7) << 4)));
  float run[8] = {0.f, 0.f, 0.f, 0.f, 0.f, 0.f, 0.f, 0.f};
  for (int c = 0; c < NCH; ++c) {
    uint4 v = *(const uint4*)(srcb + (size_t)c * 16384);
    union { unsigned short u[8]; uint4 q; } o;
    #pragma unroll
    for (int i = 0; i < 8; ++i) o.u[i] = f2bf(run[i]);
    *(uint4*)(dstb + (size_t)c * 32768) = o.q;
    const unsigned short* pv = (const unsigned short*)&v;
    #pragma unroll
    for (int i = 0; i < 8; ++i) run[i] += bf2f(pv[i]);
  }
  if (part == 0) {
    for (int e = t; e < MM; e += 256) {
      float zr = 0.f;
      for (int c = 0; c < NCH; ++c) {
        size_t idx = (size_t)slice * NCH * MM + (size_t)c * MM + e;
        float x = wsZ[idx];
        wsZ[idx] = zr;
        zr += x;
      }
    }
  }
}

// ---------------- phase3: MFMA outputs per (b,h,chunk) ----------------
// LDS: U0 16K (RFT half / ST half / Amask+VT) | QP 16K | KP 16K | ZL 1K
__global__ __launch_bounds__(256) void phase3_kernel(const float* __restrict__ Qin,
                                                     const float* __restrict__ Kin,
                                                     const float* __restrict__ Vin,
                                                     const unsigned short* __restrict__ RFTg,
                                                     const unsigned short* __restrict__ wsPb,
                                                     const float* __restrict__ wsZ,
                                                     const unsigned int* __restrict__ wsu,
                                                     float* __restrict__ Out,
                                                     int bh0) {
  __shared__ __align__(16) char lds[50176];
  char* U0  = lds;
  char* QPl = lds + 16384;
  char* KPl = lds + 32768;
  float* ZL = (float*)(lds + 49152);

  int slice = blockIdx.x / NCH;
  int c     = blockIdx.x % NCH;
  int bh = bh0 + slice, b = bh >> 4, h = bh & 15;
  const int t    = threadIdx.x;
  const int lane = t & 63;
  const int w    = t >> 6;

  ZL[t] = wsZ[(size_t)(slice * NCH + c) * MM + t];
  float kst = dec_key(*wsu);

  const int rloc = lane & 15;
  const int kc0  = (lane >> 4) * 8;
  const int arow = 16 * w + rloc;
  const float* qrow = Qin + ((size_t)(b * LL + c * CC + arow)) * DM + h * DH;
  const float* krow = Kin + ((size_t)(b * LL + c * CC + arow)) * DM + h * DH;

  s16x8 qfrag[2], kfrag[2];
  float ss = 0.f;
  #pragma unroll
  for (int kf = 0; kf < 2; ++kf) {
    float4 qa_ = *(const float4*)(qrow + kf * 32 + kc0);
    float4 qb_ = *(const float4*)(qrow + kf * 32 + kc0 + 4);
    float4 ka_ = *(const float4*)(krow + kf * 32 + kc0);
    float4 kb_ = *(const float4*)(krow + kf * 32 + kc0 + 4);
    float qs[8] = {qa_.x, qa_.y, qa_.z, qa_.w, qb_.x, qb_.y, qb_.z, qb_.w};
    float ks[8] = {ka_.x, ka_.y, ka_.z, ka_.w, kb_.x, kb_.y, kb_.z, kb_.w};
    #pragma unroll
    for (int i = 0; i < 8; ++i) {
      float qv = qs[i] * SCALE, kv = ks[i] * SCALE;
      ss += kv * kv;
      qfrag[kf][i] = (short)f2bf(qv);
      kfrag[kf][i] = (short)f2bf(kv);
    }
  }
  ss += __shfl_xor(ss, 16, 64);
  ss += __shfl_xor(ss, 32, 64);
  float hkv = -0.5f * ss;

  f32x4 Aacc[4], Oacc[4];
  #pragma unroll
  for (int i = 0; i < 4; ++i) { Aacc[i] = (f32x4)0.f; Oacc[i] = (f32x4)0.f; }
  float den1[4] = {0.f, 0.f, 0.f, 0.f};
  float den2[4] = {0.f, 0.f, 0.f, 0.f};

  float hkb[4];
  #pragma unroll
  for (int r = 0; r < 4; ++r)
    hkb[r] = __shfl(hkv, (lane >> 4) * 4 + r, 64) - kst + LNCF;  // folded

  const unsigned lgrp16 = (unsigned)((lane >> 4) * 16);

  for (int h2 = 0; h2 < 2; ++h2) {
    __syncthreads();                       // U0 free (prev O2 reads done)
    {  // copy RFT half (pre-swizzled) -> U0, linear
      const uint4* src = (const uint4*)(RFTg + (size_t)h2 * 8192);
      uint4* dst = (uint4*)U0;
      #pragma unroll
      for (int r2 = 0; r2 < 4; ++r2) dst[t + 256 * r2] = src[t + 256 * r2];
    }
    __syncthreads();

    // ---- projections: P = Qs*RF, Ks*RF for this m-half ----
    f32x4 pq[8], pk[8];
    #pragma unroll
    for (int i = 0; i < 8; ++i) { pq[i] = (f32x4)0.f; pk[i] = (f32x4)0.f; }
    #pragma unroll
    for (int mt = 0; mt < 8; ++mt) {
      int mloc = mt * 16 + rloc;
      unsigned rbyte = (unsigned)(mloc * 128);
      unsigned swz = (unsigned)((mloc & 7) << 4);
      #pragma unroll
      for (int kf = 0; kf < 2; ++kf) {
        s16x8 bf_ = *(const s16x8*)(U0 + rbyte + (((unsigned)(kf * 64) + lgrp16) ^ swz));
        pq[mt] = __builtin_amdgcn_mfma_f32_16x16x32_bf16(qfrag[kf], bf_, pq[mt], 0, 0, 0);
        pk[mt] = __builtin_amdgcn_mfma_f32_16x16x32_bf16(kfrag[kf], bf_, pk[mt], 0, 0, 0);
      }
    }
    // ---- exp, pack to QP/KP, den2 partials ----
    #pragma unroll
    for (int mt = 0; mt < 8; ++mt) {
      int mloc = mt * 16 + rloc;
      #pragma unroll
      for (int r = 0; r < 4; ++r) {
        int row = 16 * w + (lane >> 4) * 4 + r;
        float qpv = __expf(pq[mt][r] + LNCF) + NCFK;
        float kpv = __expf(hkb[r] + pk[mt][r]) + NCFK;
        unsigned byte = (unsigned)(row * 256) +
                        (((unsigned)(mloc * 2)) ^ ((unsigned)((row & 7) << 4)));
        *(unsigned short*)(QPl + byte) = f2bf(qpv);
        *(unsigned short*)(KPl + byte) = f2bf(kpv);
        den2[r] += qpv * ZL[h2 * 128 + mloc];
      }
    }
    __syncthreads();

    // ---- issue S_prev-half copy (pre-swizzled bf16 from scan) ----
    uint4 stmp[4];
    {
      const char* ssrc = (const char*)wsPb + ((size_t)(slice * NCH + c) * 2 + h2) * 16384;
      #pragma unroll
      for (int r2 = 0; r2 < 4; ++r2)
        stmp[r2] = *(const uint4*)(ssrc + t * 16 + r2 * 4096);
    }

    // ---- Qp A-frags (reused for A-MFMA and O2) ----
    s16x8 qa[4];
    {
      unsigned rbyte = (unsigned)(arow * 256);
      unsigned swz = (unsigned)((arow & 7) << 4);
      #pragma unroll
      for (int kf = 0; kf < 4; ++kf)
        qa[kf] = *(const s16x8*)(QPl + rbyte + (((unsigned)(kf * 64) + lgrp16) ^ swz));
    }
    // ---- A += Qp * Kp^T (only tiles ct <= w are unmasked) ----
    for (int ct = 0; ct <= w; ++ct) {
      int rowb = ct * 16 + rloc;
      unsigned rbyte = (unsigned)(rowb * 256);
      unsigned swz = (unsigned)((rowb & 7) << 4);
      #pragma unroll
      for (int kf = 0; kf < 4; ++kf) {
        s16x8 bf_ = *(const s16x8*)(KPl + rbyte + (((unsigned)(kf * 64) + lgrp16) ^ swz));
        Aacc[ct] = __builtin_amdgcn_mfma_f32_16x16x32_bf16(qa[kf], bf_, Aacc[ct], 0, 0, 0);
      }
    }
    // ---- write ST half -> U0 (already swizzled layout) ----
    {
      uint4* u0v = (uint4*)U0;
      #pragma unroll
      for (int r2 = 0; r2 < 4; ++r2) u0v[t + 256 * r2] = stmp[r2];
    }
    __syncthreads();

    // ---- O += Qp * S_prev ----
    #pragma unroll
    for (int ct = 0; ct < 4; ++ct) {
      int rowb = ct * 16 + rloc;   // d-row of ST
      unsigned rbyte = (unsigned)(rowb * 256);
      unsigned swz = (unsigned)((rowb & 7) << 4);
      #pragma unroll
      for (int kf = 0; kf < 4; ++kf) {
        s16x8 bf_ = *(const s16x8*)(U0 + rbyte + (((unsigned)(kf * 64) + lgrp16) ^ swz));
        Oacc[ct] = __builtin_amdgcn_mfma_f32_16x16x32_bf16(qa[kf], bf_, Oacc[ct], 0, 0, 0);
      }
    }
  }

  __syncthreads();  // U0 free again (O2 reads done)

  // ---- mask A, den1 partials, write Amask (bf16, swizzled) at U0[0..8K) ----
  #pragma unroll
  for (int ct = 0; ct < 4; ++ct) {
    #pragma unroll
    for (int r = 0; r < 4; ++r) {
      int row = 16 * w + (lane >> 4) * 4 + r;
      int col = ct * 16 + rloc;
      float av = (ct <= w && col <= row) ? Aacc[ct][r] : 0.f;
      den1[r] += av;
      unsigned byte = (unsigned)(row * 128) +
                      (((unsigned)(col * 2)) ^ ((unsigned)((row & 7) << 4)));
      *(unsigned short*)(U0 + byte) = f2bf(av);
    }
  }
  // ---- transpose V -> U0[8K..16K) (bf16, swizzled) ----
  {
    const float* vbase = Vin + ((size_t)(b * LL + c * CC + w * 16)) * DM + h * DH + lane;
    float vv[16];
    #pragma unroll
    for (int i = 0; i < 16; ++i) vv[i] = vbase[(size_t)i * DM];
    unsigned swz = (unsigned)((lane & 7) << 4);
    #pragma unroll
    for (int q = 0; q < 2; ++q) {
      union { unsigned short u[8]; uint4 v; } pk_;
      #pragma unroll
      for (int i = 0; i < 8; ++i) pk_.u[i] = f2bf(vv[q * 8 + i]);
      unsigned byte = 8192u + (unsigned)(lane * 128) + (((unsigned)(w * 32 + q * 16)) ^ swz);
      *(uint4*)(U0 + byte) = pk_.v;
    }
  }
  __syncthreads();

  // ---- O += mask(A) * V ----
  {
    int nkf = (w >= 2) ? 2 : 1;
    unsigned arbyte = (unsigned)(arow * 128);
    unsigned aswz = (unsigned)((arow & 7) << 4);
    for (int kf = 0; kf < nkf; ++kf) {
      s16x8 af = *(const s16x8*)(U0 + arbyte + (((unsigned)(kf * 64) + lgrp16) ^ aswz));
      #pragma unroll
      for (int ct = 0; ct < 4; ++ct) {
        int rowv = ct * 16 + rloc;
        unsigned byte = 8192u + (unsigned)(rowv * 128) +
                        (((unsigned)(kf * 64) + lgrp16) ^ ((unsigned)((rowv & 7) << 4)));
        s16x8 vf = *(const s16x8*)(U0 + byte);
        Oacc[ct] = __builtin_amdgcn_mfma_f32_16x16x32_bf16(af, vf, Oacc[ct], 0, 0, 0);
      }
    }
  }

  // ---- denominator reduce + epilogue ----
  float inv[4];
  #pragma unroll
  for (int r = 0; r < 4; ++r) {
    float dv = den1[r] + den2[r];
    dv += __shfl_xor(dv, 1, 64);
    dv += __shfl_xor(dv, 2, 64);
    dv += __shfl_xor(dv, 4, 64);
    dv += __shfl_xor(dv, 8, 64);
    if (fabsf(dv) <= NSTB) dv += 2.f * NSTB;
    inv[r] = 1.0f / dv;
  }
  #pragma unroll
  for (int r = 0; r < 4; ++r) {
    int row = 16 * w + (lane >> 4) * 4 + r;
    size_t g = ((size_t)(b * LL + c * CC + row)) * DM + h * DH;
    #pragma unroll
    for (int ct = 0; ct < 4; ++ct) {
      Out[g + ct * 16 + rloc] = Oacc[ct][r] * inv[r];
    }
  }
}

extern "C" void kernel_launch(void* const* d_in, const int* in_sizes, int n_in,
                              void* d_out, int out_size, void* d_ws, size_t ws_size,
                              hipStream_t stream) {
  const float* Q  = (const float*)d_in[0];
  const float* K  = (const float*)d_in[1];
  const float* V  = (const float*)d_in[2];
  const float* RF = (const float*)d_in[3];
  float* Out = (float*)d_out;
  unsigned int* wsu = (unsigned int*)d_ws;

  const size_t RESV = 1024;
  const size_t RFTB = 32768;  // RFTg bf16 [256][64] swizzled
  const size_t perSlice = (size_t)NCH * 16384 * 2   // wsSb bytes
                        + (size_t)NCH * 2 * 16384   // wsPb bytes
                        + (size_t)NCH * MM * 4;     // wsZ bytes
  int G = BB * HH;  // 64
  while (G > 1 && RESV + RFTB + (size_t)G * perSlice > ws_size) G >>= 1;

  unsigned short* RFTg = (unsigned short*)((char*)d_ws + RESV);
  unsigned short* wsSb = (unsigned short*)((char*)d_ws + RESV + RFTB);
  unsigned short* wsPb = wsSb + (size_t)G * NCH * 16384;
  float* wsZ = (float*)((char*)wsPb + (size_t)G * NCH * 2 * 16384);

  hipMemsetAsync(d_ws, 0, 4, stream);  // init k_stab atomicMax key
  hipLaunchKernelGGL(kstab_kernel, dim3(2048), dim3(256), 0, stream, K, wsu);
  hipLaunchKernelGGL(rft_prep, dim3(1), dim3(256), 0, stream, RF, RFTg);
  for (int bh0 = 0; bh0 < BB * HH; bh0 += G) {
    hipLaunchKernelGGL(phase1_kernel, dim3(G * NCH), dim3(256), 0, stream,
                       K, V, RFTg, wsSb, wsZ, wsu, bh0);
    hipLaunchKernelGGL(scan_kernel, dim3(G * 8), dim3(256), 0, stream, wsSb, wsPb, wsZ);
    hipLaunchKernelGGL(phase3_kernel, dim3(G * NCH), dim3(256), 0, stream,
                       Q, K, V, RFTg, wsPb, wsZ, wsu, Out, bh0);
  }
}